// Round 5
// baseline (44542.694 us; speedup 1.0000x reference)
//
#include <hip/hip_runtime.h>
#include <cstdint>
#include <cstddef>

#define T_STEPS 1000
#define NU 512
#define NC 14

typedef unsigned short ushort_t;
typedef unsigned int uint_t;
typedef __attribute__((ext_vector_type(8))) short bf16x8;
typedef __attribute__((ext_vector_type(4))) float f32x4;

// ---- ws byte offsets ----
// bp0: [128 ntile][19 s][64 lane][8] bf16 hi/lo   (K0 = 96 x-pad + 512 h = 608 = 19*32)
// bp1: [128 ntile][32 s][64 lane][8] bf16 hi/lo   (K1 = 512 G1 + 512 U1 = 1024 = 32*32)
#define OFF_BP0H  0u
#define OFF_BP0L  (OFF_BP0H + 128u*9728u*2u)
#define OFF_BP1H  (OFF_BP0L + 128u*9728u*2u)
#define OFF_BP1L  (OFF_BP1H + 128u*16384u*2u)
#define OFF_S1P   (OFF_BP1L + 128u*16384u*2u)
#define OFF_ZB1P  (OFF_S1P  + 2048u*4u)
#define OFF_B0P   (OFF_ZB1P + 2048u*4u)
#define OFF_WFT   (OFF_B0P  + 2048u*4u)
#define OFF_H0H   (OFF_WFT  + 14u*512u*4u)       /* [2][128][512] ushort */
#define OFF_H0L   (OFF_H0H  + 2u*128u*512u*2u)
#define OFF_H1H   (OFF_H0L  + 2u*128u*512u*2u)
#define OFF_H1L   (OFF_H1H  + 2u*128u*512u*2u)
#define OFF_BAR   (OFF_H1L  + 2u*128u*512u*2u)

// ---------------- bf16 helpers ----------------
__device__ __host__ __forceinline__ float bf2f(short s) {
    unsigned u = ((unsigned)(unsigned short)s) << 16;
    return __builtin_bit_cast(float, u);
}
__device__ __forceinline__ ushort_t f2bf(float f) {
    unsigned u = __float_as_uint(f);
    u = u + 0x7FFFu + ((u >> 16) & 1u);   // RNE
    return (ushort_t)(u >> 16);
}

// ---------------- weight packing ----------------
// fragment element (ntile, s, lane l, j): k = s*32 + (l>>4)*8 + j ; col c = l&15
// zcol = ntile*4 + (c>>2) + 512*(c&3)
__global__ void pack0_kernel(const float* __restrict__ w0, const float* __restrict__ u0,
                             ushort_t* __restrict__ bp0h, ushort_t* __restrict__ bp0l)
{
    const int ntile = blockIdx.x;
    const int l = threadIdx.x & 63;
    const int c = l & 15, koff = (l >> 4) * 8;
    const int zcol = ntile * 4 + (c >> 2) + 512 * (c & 3);
    for (int s = (threadIdx.x >> 6); s < 19; s += 4) {
        bf16x8 hv, lv;
#pragma unroll
        for (int j = 0; j < 8; ++j) {
            int k = s * 32 + koff + j;
            float v;
            if (k < 96) v = (k < 72) ? w0[(size_t)k * 2048 + zcol] : 0.f;
            else        v = u0[(size_t)(k - 96) * 2048 + zcol];
            ushort_t hi = f2bf(v);
            ushort_t lo = f2bf(v - bf2f((short)hi));
            hv[j] = (short)hi; lv[j] = (short)lo;
        }
        size_t di = ((size_t)(ntile * 19 + s) * 64 + l) * 8;
        *(bf16x8*)&bp0h[di] = hv;
        *(bf16x8*)&bp0l[di] = lv;
    }
}

__global__ void pack1_kernel(const float* __restrict__ w1, const float* __restrict__ u1,
                             const float* __restrict__ gamma,
                             ushort_t* __restrict__ bp1h, ushort_t* __restrict__ bp1l)
{
    const int ntile = blockIdx.x;
    const int l = threadIdx.x & 63;
    const int c = l & 15, koff = (l >> 4) * 8;
    const int zcol = ntile * 4 + (c >> 2) + 512 * (c & 3);
    for (int s = (threadIdx.x >> 6); s < 32; s += 4) {
        bf16x8 hv, lv;
#pragma unroll
        for (int j = 0; j < 8; ++j) {
            int k = s * 32 + koff + j;
            float v = (k < 512) ? gamma[k] * w1[(size_t)k * 2048 + zcol]
                                : u1[(size_t)(k - 512) * 2048 + zcol];
            ushort_t hi = f2bf(v);
            ushort_t lo = f2bf(v - bf2f((short)hi));
            hv[j] = (short)hi; lv[j] = (short)lo;
        }
        size_t di = ((size_t)(ntile * 32 + s) * 64 + l) * 8;
        *(bf16x8*)&bp1h[di] = hv;
        *(bf16x8*)&bp1l[di] = lv;
    }
}

__global__ void sums_kernel(const float* __restrict__ w1, const float* __restrict__ gamma,
                            const float* __restrict__ beta, const float* __restrict__ b0,
                            const float* __restrict__ b1,
                            float* __restrict__ s1p, float* __restrict__ zb1p,
                            float* __restrict__ b0p)
{
    int zcol = blockIdx.x * 256 + threadIdx.x;   // 8 blocks * 256
    float gs = 0.f, bs = 0.f;
    for (int k = 0; k < NU; k++) {
        float w = w1[(size_t)k * 2048 + zcol];
        gs += gamma[k] * w;
        bs += beta[k] * w;
    }
    int g = zcol >> 9, r = zcol & 511, nt = r >> 2, u = r & 3;
    int pc = nt * 16 + u * 4 + g;
    s1p[pc]  = gs;
    zb1p[pc] = b1[zcol] + bs;
    b0p[pc]  = b0[zcol];
}

__global__ void wft_kernel(const float* __restrict__ wf, float* __restrict__ wfT)
{
    int i = blockIdx.x * 512 + threadIdx.x;   // 14 blocks * 512
    if (i < NC * NU) {
        int c = i >> 9, u = i & 511;
        wfT[c * NU + u] = wf[(size_t)u * NC + c];
    }
}

__global__ void init_kernel(char* __restrict__ ws)
{
    size_t i = (size_t)blockIdx.x * 1024 + threadIdx.x;   // 256*1024 = 262144
    uint_t* st = (uint_t*)(ws + OFF_H0H);                  // 1 MB of h-state = 262144 u32
    if (i < 262144) st[i] = 0u;
    if (i == 0) *(unsigned*)(ws + OFF_BAR) = 0u;
}

// ---------------- device helpers ----------------
__device__ __forceinline__ float sigf(float x)     { return 1.f / (1.f + __expf(-x)); }
__device__ __forceinline__ float tanhfast(float x) { return 2.f / (1.f + __expf(-2.f * x)) - 1.f; }

__device__ __forceinline__ void grid_barrier(unsigned* bar)
{
    __syncthreads();
    if (threadIdx.x == 0) {
        __threadfence();
        unsigned old = __hip_atomic_fetch_add(bar, 1u, __ATOMIC_RELAXED, __HIP_MEMORY_SCOPE_AGENT);
        unsigned target = (old | 255u) + 1u;
        while (__hip_atomic_load(bar, __ATOMIC_RELAXED, __HIP_MEMORY_SCOPE_AGENT) < target)
            __builtin_amdgcn_s_sleep(2);
        __threadfence();
    }
    __syncthreads();
}

// softmax head for one batch row; h1 stored as bf16 hi/lo [128][512]
__device__ void ypass(const ushort_t* __restrict__ h1h, const ushort_t* __restrict__ h1l,
                      const float* __restrict__ wfT, const float* __restrict__ bf,
                      float* __restrict__ out, int b, int tw, int lane)
{
    bf16x8 hh = *(const bf16x8*)(h1h + (size_t)b * NU + lane * 8);
    bf16x8 hl = *(const bf16x8*)(h1l + (size_t)b * NU + lane * 8);
    float hv[8];
#pragma unroll
    for (int j = 0; j < 8; ++j) hv[j] = bf2f(hh[j]) + bf2f(hl[j]);
    float z[NC];
#pragma unroll
    for (int c = 0; c < NC; ++c) {
        const float* wp = wfT + c * NU + lane * 8;
        float a = 0.f;
#pragma unroll
        for (int j = 0; j < 8; ++j) a = fmaf(hv[j], wp[j], a);
        z[c] = a;
    }
#pragma unroll
    for (int off = 32; off > 0; off >>= 1) {
#pragma unroll
        for (int c = 0; c < NC; ++c) z[c] += __shfl_xor(z[c], off);
    }
    if (lane == 0) {
        float m = -1e30f;
#pragma unroll
        for (int c = 0; c < NC; ++c) { z[c] += bf[c]; m = fmaxf(m, z[c]); }
        float s = 0.f, e[NC];
#pragma unroll
        for (int c = 0; c < NC; ++c) { e[c] = __expf(z[c] - m); s += e[c]; }
        float inv = 1.f / s;
        float* o = out + ((size_t)b * T_STEPS + tw) * NC;
#pragma unroll
        for (int c = 0; c < NC; ++c) o[c] = e[c] * inv;
    }
}

// ---------------- main persistent kernel ----------------
// grid 256 = mtile(2) x ntile(128); 512 threads = 8 waves: m = w&3 (M-subtile), kw = w>>2
// each wave: one 16x16 MFMA tile, 3-pass split-bf16, K halved across kw
#define MFMA(A,B,C) __builtin_amdgcn_mfma_f32_16x16x32_bf16((A),(B),(C),0,0,0)

__global__ __launch_bounds__(512, 1)
void lstm_main(const float* __restrict__ x, const float* __restrict__ bf,
               char* __restrict__ ws, float* __restrict__ out)
{
    __shared__ __attribute__((aligned(16))) ushort_t bpAh[19*512];   // 19,456 B
    __shared__ __attribute__((aligned(16))) ushort_t bpAl[19*512];
    __shared__ __attribute__((aligned(16))) ushort_t bpBh[32*512];   // 32,768 B
    __shared__ __attribute__((aligned(16))) ushort_t bpBl[32*512];
    __shared__ __attribute__((aligned(16))) ushort_t xsh[12*512];    // 12,288 B (x frags, 4m x 3s)
    __shared__ __attribute__((aligned(16))) ushort_t xsl[12*512];
    __shared__ float zexf[2*64*17];                                  // 8,704 B
    __shared__ float sqs[64], sqq[64];

    const ushort_t* __restrict__ bp0h = (const ushort_t*)(ws + OFF_BP0H);
    const ushort_t* __restrict__ bp0l = (const ushort_t*)(ws + OFF_BP0L);
    const ushort_t* __restrict__ bp1h = (const ushort_t*)(ws + OFF_BP1H);
    const ushort_t* __restrict__ bp1l = (const ushort_t*)(ws + OFF_BP1L);
    const float* __restrict__ s1p  = (const float*)(ws + OFF_S1P);
    const float* __restrict__ zb1p = (const float*)(ws + OFF_ZB1P);
    const float* __restrict__ b0p  = (const float*)(ws + OFF_B0P);
    const float* __restrict__ wfT  = (const float*)(ws + OFF_WFT);
    ushort_t* h0h = (ushort_t*)(ws + OFF_H0H);
    ushort_t* h0l = (ushort_t*)(ws + OFF_H0L);
    ushort_t* h1h = (ushort_t*)(ws + OFF_H1H);
    ushort_t* h1l = (ushort_t*)(ws + OFF_H1L);
    unsigned* bar = (unsigned*)(ws + OFF_BAR);

    const int tid = threadIdx.x;
    const int l   = tid & 63;
    const int w   = tid >> 6;
    const int m   = w & 3;            // M-subtile (16 rows)
    const int kw  = w >> 2;           // K-half
    const int rr  = l & 15;
    const int koff = (l >> 4) * 8;
    const int blk = blockIdx.x, mtile = blk & 1, ntile = blk >> 1;
    const int rb = mtile * 64;
    const int rowA = rb + m * 16 + rr;      // absolute batch row of this lane's A-frag

    // ---- one-time LDS weight fill ----
    {
        const uint_t* s0h = (const uint_t*)bp0h + (size_t)ntile * 4864;
        const uint_t* s0l = (const uint_t*)bp0l + (size_t)ntile * 4864;
        uint_t* d0h = (uint_t*)bpAh; uint_t* d0l = (uint_t*)bpAl;
        for (int i = tid; i < 4864; i += 512) { d0h[i] = s0h[i]; d0l[i] = s0l[i]; }
        const uint_t* s1h = (const uint_t*)bp1h + (size_t)ntile * 8192;
        const uint_t* s1l = (const uint_t*)bp1l + (size_t)ntile * 8192;
        uint_t* d1h = (uint_t*)bpBh; uint_t* d1l = (uint_t*)bpBl;
        for (int i = tid; i < 8192; i += 512) { d1h[i] = s1h[i]; d1l[i] = s1l[i]; }
    }

    // epilogue-thread constants & register c-state (tid<256: eb=row, eu=unit 0..3)
    const int eb = tid & 63, eu = (tid >> 6) & 3;
    float c0v = 0.f, c1v = 0.f;
    f32x4 b0v = {0,0,0,0}, s1v = {0,0,0,0}, zbv = {0,0,0,0};
    if (tid < 256) {
        b0v = *(const f32x4*)&b0p[ntile * 16 + eu * 4];
        s1v = *(const f32x4*)&s1p[ntile * 16 + eu * 4];
        zbv = *(const f32x4*)&zb1p[ntile * 16 + eu * 4];
    }
    __syncthreads();

#pragma unroll 1
    for (int t = 0; t < T_STEPS; ++t) {
        const int cur = t & 1, prv = cur ^ 1;
        ushort_t* __restrict__       h0h_cur = h0h + cur * 65536;
        ushort_t* __restrict__       h0l_cur = h0l + cur * 65536;
        const ushort_t* __restrict__ h0h_prv = h0h + prv * 65536;
        const ushort_t* __restrict__ h0l_prv = h0l + prv * 65536;
        ushort_t* __restrict__       h1h_cur = h1h + cur * 65536;
        ushort_t* __restrict__       h1l_cur = h1l + cur * 65536;
        const ushort_t* __restrict__ h1h_prv = h1h + prv * 65536;
        const ushort_t* __restrict__ h1l_prv = h1l + prv * 65536;

        // ---- stage x_t as bf16 hi/lo fragments into LDS ----
        for (int i = tid; i < 3072; i += 512) { ((uint_t*)xsh)[i] = 0u; ((uint_t*)xsl)[i] = 0u; }
        __syncthreads();
#pragma unroll
        for (int i = 0; i < 9; ++i) {
            int e = tid + i * 512;                    // 0..4607 = 64 rows x 72 feats
            int row = e / 72, k = e - row * 72;
            float v = x[(size_t)(rb + row) * 72000 + (size_t)t * 72 + k];
            ushort_t hi = f2bf(v);
            ushort_t lo = f2bf(v - bf2f((short)hi));
            int di = (((row >> 4) * 3 + (k >> 5)) * 64 + ((k >> 3) & 3) * 16 + (row & 15)) * 8 + (k & 7);
            xsh[di] = hi; xsl[di] = lo;
        }
        __syncthreads();

        // ================= PHASE A: z0 = [x_t | h0prev] @ Bp0 =================
        {
            f32x4 aHH = {0,0,0,0}, aLH = {0,0,0,0}, aHL = {0,0,0,0};
            if (kw == 0) {
#pragma unroll
                for (int s = 0; s < 3; ++s) {
                    bf16x8 ah = *(const bf16x8*)&xsh[((m * 3 + s) * 64 + l) * 8];
                    bf16x8 al = *(const bf16x8*)&xsl[((m * 3 + s) * 64 + l) * 8];
                    bf16x8 bh = *(const bf16x8*)&bpAh[s * 512 + l * 8];
                    bf16x8 bl = *(const bf16x8*)&bpAl[s * 512 + l * 8];
                    aHH = MFMA(ah, bh, aHH); aLH = MFMA(al, bh, aLH); aHL = MFMA(ah, bl, aHL);
                }
#pragma unroll
                for (int s = 3; s < 10; ++s) {
                    const int ko = (s - 3) * 32 + koff;
                    bf16x8 ah = *(const bf16x8*)(h0h_prv + rowA * 512 + ko);
                    bf16x8 al = *(const bf16x8*)(h0l_prv + rowA * 512 + ko);
                    bf16x8 bh = *(const bf16x8*)&bpAh[s * 512 + l * 8];
                    bf16x8 bl = *(const bf16x8*)&bpAl[s * 512 + l * 8];
                    aHH = MFMA(ah, bh, aHH); aLH = MFMA(al, bh, aLH); aHL = MFMA(ah, bl, aHL);
                }
            } else {
#pragma unroll
                for (int s = 10; s < 19; ++s) {
                    const int ko = (s - 3) * 32 + koff;
                    bf16x8 ah = *(const bf16x8*)(h0h_prv + rowA * 512 + ko);
                    bf16x8 al = *(const bf16x8*)(h0l_prv + rowA * 512 + ko);
                    bf16x8 bh = *(const bf16x8*)&bpAh[s * 512 + l * 8];
                    bf16x8 bl = *(const bf16x8*)&bpAl[s * 512 + l * 8];
                    aHH = MFMA(ah, bh, aHH); aLH = MFMA(al, bh, aLH); aHL = MFMA(ah, bl, aHL);
                }
            }
            f32x4 zv = aHH + aLH + aHL;
#pragma unroll
            for (int r = 0; r < 4; ++r)
                zexf[kw * 1088 + (m * 16 + (l >> 4) * 4 + r) * 17 + rr] = zv[r];
        }
        __syncthreads();
        // epilogue A (layer-0 gates; c0 in registers)
        if (tid < 256) {
            float z[4];
#pragma unroll
            for (int g = 0; g < 4; ++g)
                z[g] = zexf[eb * 17 + eu * 4 + g] + zexf[1088 + eb * 17 + eu * 4 + g];
            z[0] += b0v.x; z[1] += b0v.y; z[2] += b0v.z; z[3] += b0v.w;
            float ig = sigf(z[0]), fg = sigf(z[1]), gg = tanhfast(z[2]), og = sigf(z[3]);
            float cn = fg * c0v + ig * gg;
            c0v = cn;
            float hval = og * tanhfast(cn);
            ushort_t hi = f2bf(hval);
            ushort_t lo = f2bf(hval - bf2f((short)hi));
            int hidx = (rb + eb) * 512 + ntile * 4 + eu;
            h0h_cur[hidx] = hi; h0l_cur[hidx] = lo;
        }

        grid_barrier(bar);   // ---- the ONE global sync per step ----

        // ====== PHASE B: z1 = h0@G1 (kw=0, + LN stats fused) + h1prev@U1 (kw=1) ======
        {
            f32x4 bHH = {0,0,0,0}, bLH = {0,0,0,0}, bHL = {0,0,0,0};
            const ushort_t* __restrict__ Ah = kw ? h1h_prv : h0h_cur;
            const ushort_t* __restrict__ Al = kw ? h1l_prv : h0l_cur;
            float sa = 0.f, qa = 0.f;
#pragma unroll
            for (int s2 = 0; s2 < 16; ++s2) {
                const int ko = s2 * 32 + koff;
                bf16x8 ah = *(const bf16x8*)(Ah + rowA * 512 + ko);
                bf16x8 al = *(const bf16x8*)(Al + rowA * 512 + ko);
                const int sb = (kw * 16 + s2) * 512 + l * 8;
                bf16x8 bh = *(const bf16x8*)&bpBh[sb];
                bf16x8 bl = *(const bf16x8*)&bpBl[sb];
                bHH = MFMA(ah, bh, bHH); bLH = MFMA(al, bh, bLH); bHL = MFMA(ah, bl, bHL);
                if (kw == 0) {   // LN stats from the same fragments (zero extra traffic)
#pragma unroll
                    for (int j = 0; j < 8; ++j) {
                        float hv = bf2f(ah[j]) + bf2f(al[j]);
                        sa += hv; qa = fmaf(hv, hv, qa);
                    }
                }
            }
            if (kw == 0) {
                sa += __shfl_xor(sa, 16); sa += __shfl_xor(sa, 32);
                qa += __shfl_xor(qa, 16); qa += __shfl_xor(qa, 32);
                if (l < 16) { sqs[m * 16 + l] = sa; sqq[m * 16 + l] = qa; }
            }
            f32x4 zv = bHH + bLH + bHL;
#pragma unroll
            for (int r = 0; r < 4; ++r)
                zexf[kw * 1088 + (m * 16 + (l >> 4) * 4 + r) * 17 + rr] = zv[r];
        }
        __syncthreads();

        // softmax head for step t-1 (blocks 0..127, wave 7 — no epilogue duty)
        if (blk < 128 && w == 7 && t > 0)
            ypass(h1h_prv, h1l_prv, wfT, bf, out, blk, t - 1, l);

        // epilogue B (LN folded via fused stats; c1 in registers)
        if (tid < 256) {
            float mu = sqs[eb] * (1.f / 512.f);
            float rs = rsqrtf(sqq[eb] * (1.f / 512.f) - mu * mu + 1e-3f);
            float z[4];
#pragma unroll
            for (int g = 0; g < 4; ++g) {
                float zG = zexf[eb * 17 + eu * 4 + g];
                float zU = zexf[1088 + eb * 17 + eu * 4 + g];
                float s1g = (g == 0) ? s1v.x : (g == 1) ? s1v.y : (g == 2) ? s1v.z : s1v.w;
                float zbg = (g == 0) ? zbv.x : (g == 1) ? zbv.y : (g == 2) ? zbv.z : zbv.w;
                z[g] = rs * (zG - mu * s1g) + zU + zbg;
            }
            float ig = sigf(z[0]), fg = sigf(z[1]), gg = tanhfast(z[2]), og = sigf(z[3]);
            float cn = fg * c1v + ig * gg;
            c1v = cn;
            float hval = og * tanhfast(cn);
            ushort_t hi = f2bf(hval);
            ushort_t lo = f2bf(hval - bf2f((short)hi));
            int hidx = (rb + eb) * 512 + ntile * 4 + eu;
            h1h_cur[hidx] = hi; h1l_cur[hidx] = lo;
        }
        // cross-iteration LDS anti-deps are covered by the staging syncthreads at loop top
    }

    grid_barrier(bar);
    if (blk < 128 && w == 7)
        ypass(h1h + ((T_STEPS - 1) & 1) * 65536, h1l + ((T_STEPS - 1) & 1) * 65536,
              wfT, bf, out, blk, T_STEPS - 1, l);
}

// ---------------- launcher ----------------
extern "C" void kernel_launch(void* const* d_in, const int* in_sizes, int n_in,
                              void* d_out, int out_size, void* d_ws, size_t ws_size,
                              hipStream_t stream)
{
    const float* x     = (const float*)d_in[0];
    const float* w0    = (const float*)d_in[1];
    const float* u0    = (const float*)d_in[2];
    const float* b0    = (const float*)d_in[3];
    const float* gamma = (const float*)d_in[4];
    const float* beta  = (const float*)d_in[5];
    const float* w1    = (const float*)d_in[6];
    const float* u1    = (const float*)d_in[7];
    const float* b1    = (const float*)d_in[8];
    const float* wf    = (const float*)d_in[9];
    const float* bf    = (const float*)d_in[10];
    float* out = (float*)d_out;
    char* ws   = (char*)d_ws;

    hipLaunchKernelGGL(pack0_kernel, dim3(128), dim3(256), 0, stream,
                       w0, u0, (ushort_t*)(ws + OFF_BP0H), (ushort_t*)(ws + OFF_BP0L));
    hipLaunchKernelGGL(pack1_kernel, dim3(128), dim3(256), 0, stream,
                       w1, u1, gamma, (ushort_t*)(ws + OFF_BP1H), (ushort_t*)(ws + OFF_BP1L));
    hipLaunchKernelGGL(sums_kernel, dim3(8), dim3(256), 0, stream,
                       w1, gamma, beta, b0, b1,
                       (float*)(ws + OFF_S1P), (float*)(ws + OFF_ZB1P), (float*)(ws + OFF_B0P));
    hipLaunchKernelGGL(wft_kernel, dim3(14), dim3(512), 0, stream, wf, (float*)(ws + OFF_WFT));
    hipLaunchKernelGGL(init_kernel, dim3(256), dim3(1024), 0, stream, ws);

    const float* xp  = x;
    const float* bfp = bf;
    char*  wsp  = ws;
    float* outp = out;
    void* args[] = { (void*)&xp, (void*)&bfp, (void*)&wsp, (void*)&outp };
    hipLaunchCooperativeKernel((void*)lstm_main, dim3(256), dim3(512), args, 0, stream);
}

// Round 6
// 35322.452 us; speedup vs baseline: 1.2610x; 1.2610x over previous
//
#include <hip/hip_runtime.h>
#include <cstdint>
#include <cstddef>

#define T_STEPS 1000
#define NU 512
#define NC 14

typedef unsigned short ushort_t;
typedef unsigned int uint_t;
typedef __attribute__((ext_vector_type(8))) short bf16x8;
typedef __attribute__((ext_vector_type(4))) float f32x4;

// ---- ws byte offsets ----
// bp0: [128 ntile][19 s][64 lane][8] bf16 hi/lo   (K0 = 96 x-pad + 512 h)
// bp1: [128 ntile][32 s][64 lane][8] bf16 hi/lo   (K1 = 512 G1 + 512 U1)
#define OFF_BP0H  0u
#define OFF_BP0L  (OFF_BP0H + 128u*9728u*2u)
#define OFF_BP1H  (OFF_BP0L + 128u*9728u*2u)
#define OFF_BP1L  (OFF_BP1H + 128u*16384u*2u)
#define OFF_S1P   (OFF_BP1L + 128u*16384u*2u)
#define OFF_ZB1P  (OFF_S1P  + 2048u*4u)
#define OFF_B0P   (OFF_ZB1P + 2048u*4u)
#define OFF_WFT   (OFF_B0P  + 2048u*4u)
#define OFF_H0H   (OFF_WFT  + 14u*512u*4u)   /* [2 buf][128 row][512 unit] ushort */
#define OFF_H0L   (OFF_H0H  + 262144u)
#define OFF_H1H   (OFF_H0L  + 262144u)
#define OFF_H1L   (OFF_H1H  + 262144u)
#define OFF_CTR   (OFF_H1L  + 262144u)       /* 32 slots x 256 B */

#define SLOT_C0SUB  0        /* + g*64 */
#define SLOT_C0ROOT (8*64)
#define SLOT_C1SUB  (16*64)  /* + g*64 */
#define SLOT_C1ROOT (24*64)

// ---------------- bf16 helpers ----------------
__device__ __forceinline__ float bf2f(short s) {
    unsigned u = ((unsigned)(unsigned short)s) << 16;
    return __builtin_bit_cast(float, u);
}
__device__ __forceinline__ ushort_t f2bf(float f) {
    unsigned u = __float_as_uint(f);
    u = u + 0x7FFFu + ((u >> 16) & 1u);   // RNE
    return (ushort_t)(u >> 16);
}

// ---------------- weight packing (layouts unchanged from r5) ----------------
__global__ void pack0_kernel(const float* __restrict__ w0, const float* __restrict__ u0,
                             ushort_t* __restrict__ bp0h, ushort_t* __restrict__ bp0l)
{
    const int ntile = blockIdx.x;
    const int l = threadIdx.x & 63;
    const int c = l & 15, koff = (l >> 4) * 8;
    const int zcol = ntile * 4 + (c >> 2) + 512 * (c & 3);
    for (int s = (threadIdx.x >> 6); s < 19; s += 4) {
        bf16x8 hv, lv;
#pragma unroll
        for (int j = 0; j < 8; ++j) {
            int k = s * 32 + koff + j;
            float v;
            if (k < 96) v = (k < 72) ? w0[(size_t)k * 2048 + zcol] : 0.f;
            else        v = u0[(size_t)(k - 96) * 2048 + zcol];
            ushort_t hi = f2bf(v);
            ushort_t lo = f2bf(v - bf2f((short)hi));
            hv[j] = (short)hi; lv[j] = (short)lo;
        }
        size_t di = ((size_t)(ntile * 19 + s) * 64 + l) * 8;
        *(bf16x8*)&bp0h[di] = hv;
        *(bf16x8*)&bp0l[di] = lv;
    }
}

__global__ void pack1_kernel(const float* __restrict__ w1, const float* __restrict__ u1,
                             const float* __restrict__ gamma,
                             ushort_t* __restrict__ bp1h, ushort_t* __restrict__ bp1l)
{
    const int ntile = blockIdx.x;
    const int l = threadIdx.x & 63;
    const int c = l & 15, koff = (l >> 4) * 8;
    const int zcol = ntile * 4 + (c >> 2) + 512 * (c & 3);
    for (int s = (threadIdx.x >> 6); s < 32; s += 4) {
        bf16x8 hv, lv;
#pragma unroll
        for (int j = 0; j < 8; ++j) {
            int k = s * 32 + koff + j;
            float v = (k < 512) ? gamma[k] * w1[(size_t)k * 2048 + zcol]
                                : u1[(size_t)(k - 512) * 2048 + zcol];
            ushort_t hi = f2bf(v);
            ushort_t lo = f2bf(v - bf2f((short)hi));
            hv[j] = (short)hi; lv[j] = (short)lo;
        }
        size_t di = ((size_t)(ntile * 32 + s) * 64 + l) * 8;
        *(bf16x8*)&bp1h[di] = hv;
        *(bf16x8*)&bp1l[di] = lv;
    }
}

__global__ void sums_kernel(const float* __restrict__ w1, const float* __restrict__ gamma,
                            const float* __restrict__ beta, const float* __restrict__ b0,
                            const float* __restrict__ b1,
                            float* __restrict__ s1p, float* __restrict__ zb1p,
                            float* __restrict__ b0p)
{
    int zcol = blockIdx.x * 256 + threadIdx.x;   // 8 blocks * 256
    float gs = 0.f, bs = 0.f;
    for (int k = 0; k < NU; k++) {
        float w = w1[(size_t)k * 2048 + zcol];
        gs += gamma[k] * w;
        bs += beta[k] * w;
    }
    int g = zcol >> 9, r = zcol & 511, nt = r >> 2, u = r & 3;
    int pc = nt * 16 + u * 4 + g;
    s1p[pc]  = gs;
    zb1p[pc] = b1[zcol] + bs;
    b0p[pc]  = b0[zcol];
}

__global__ void wft_kernel(const float* __restrict__ wf, float* __restrict__ wfT)
{
    int i = blockIdx.x * 512 + threadIdx.x;   // 14 blocks * 512
    if (i < NC * NU) {
        int c = i >> 9, u = i & 511;
        wfT[c * NU + u] = wf[(size_t)u * NC + c];
    }
}

__global__ void init_kernel(char* __restrict__ ws)
{
    size_t i = (size_t)blockIdx.x * 1024 + threadIdx.x;   // 256*1024
    uint_t* st = (uint_t*)(ws + OFF_H0H);                  // 1 MB h-state
    if (i < 262144) st[i] = 0u;
    if (i < 2048) ((uint_t*)(ws + OFF_CTR))[i] = 0u;
}

// ---------------- device helpers ----------------
__device__ __forceinline__ float sigf(float x)     { return 1.f / (1.f + __expf(-x)); }
__device__ __forceinline__ float tanhfast(float x) { return 2.f / (1.f + __expf(-2.f * x)) - 1.f; }

__device__ __forceinline__ void wait_ge(const unsigned* p, unsigned tgt)
{
    while (__hip_atomic_load(p, __ATOMIC_RELAXED, __HIP_MEMORY_SCOPE_AGENT) < tgt)
        __builtin_amdgcn_s_sleep(1);
}

// hierarchical publish: 16 blocks per sub-counter; last arriver bumps root by 16
__device__ __forceinline__ void publish(unsigned* sub, unsigned* root)
{
    unsigned old = __hip_atomic_fetch_add(sub, 1u, __ATOMIC_RELAXED, __HIP_MEMORY_SCOPE_AGENT);
    if ((old & 15u) == 15u)
        __hip_atomic_fetch_add(root, 16u, __ATOMIC_RELAXED, __HIP_MEMORY_SCOPE_AGENT);
}

// softmax head for one batch row; h1 stored as bf16 hi/lo [128][512]
__device__ void ypass(const ushort_t* __restrict__ h1h, const ushort_t* __restrict__ h1l,
                      const float* __restrict__ wfT, const float* __restrict__ bf,
                      float* __restrict__ out, int b, int tw, int lane)
{
    bf16x8 hh = *(const bf16x8*)(h1h + (size_t)b * NU + lane * 8);
    bf16x8 hl = *(const bf16x8*)(h1l + (size_t)b * NU + lane * 8);
    float hv[8];
#pragma unroll
    for (int j = 0; j < 8; ++j) hv[j] = bf2f(hh[j]) + bf2f(hl[j]);
    float z[NC];
#pragma unroll
    for (int c = 0; c < NC; ++c) {
        const float* wp = wfT + c * NU + lane * 8;
        float a = 0.f;
#pragma unroll
        for (int j = 0; j < 8; ++j) a = fmaf(hv[j], wp[j], a);
        z[c] = a;
    }
#pragma unroll
    for (int off = 32; off > 0; off >>= 1) {
#pragma unroll
        for (int c = 0; c < NC; ++c) z[c] += __shfl_xor(z[c], off);
    }
    if (lane == 0) {
        float mx = -1e30f;
#pragma unroll
        for (int c = 0; c < NC; ++c) { z[c] += bf[c]; mx = fmaxf(mx, z[c]); }
        float s = 0.f, e[NC];
#pragma unroll
        for (int c = 0; c < NC; ++c) { e[c] = __expf(z[c] - mx); s += e[c]; }
        float inv = 1.f / s;
        float* o = out + ((size_t)b * T_STEPS + tw) * NC;
#pragma unroll
        for (int c = 0; c < NC; ++c) o[c] = e[c] * inv;
    }
}

// ---------------- main persistent kernel ----------------
// blocks 0..127   : layer-0 pipeline, ntile = blk,       M=128, K=608
// blocks 128..255 : layer-1 pipeline, ntile = blk-128,   M=128, K=1024 (G1|U1)
// 8 waves/block: wave w = M-subtile (16 rows). 16x16x32 bf16 MFMA, 3-pass split.
#define MFMA(A,B,C) __builtin_amdgcn_mfma_f32_16x16x32_bf16((A),(B),(C),0,0,0)

__global__ __launch_bounds__(512, 1)
void lstm_main(const float* __restrict__ x, const float* __restrict__ bf,
               char* __restrict__ ws, float* __restrict__ out)
{
    __shared__ __attribute__((aligned(16))) unsigned char smem[98304];

    const float* __restrict__ s1p  = (const float*)(ws + OFF_S1P);
    const float* __restrict__ zb1p = (const float*)(ws + OFF_ZB1P);
    const float* __restrict__ b0p  = (const float*)(ws + OFF_B0P);
    const float* __restrict__ wfT  = (const float*)(ws + OFF_WFT);
    ushort_t* h0h = (ushort_t*)(ws + OFF_H0H);
    ushort_t* h0l = (ushort_t*)(ws + OFF_H0L);
    ushort_t* h1h = (ushort_t*)(ws + OFF_H1H);
    ushort_t* h1l = (ushort_t*)(ws + OFF_H1L);
    unsigned* ctr = (unsigned*)(ws + OFF_CTR);

    const int tid  = threadIdx.x;
    const int l    = tid & 63;
    const int w    = tid >> 6;
    const int rr   = l & 15;
    const int koff = (l >> 4) * 8;
    const int blk  = blockIdx.x;
    const int erow = tid >> 2, eu = tid & 3;   // epilogue mapping: row, unit

    unsigned* C0root = ctr + SLOT_C0ROOT;
    unsigned* C1root = ctr + SLOT_C1ROOT;

    if (blk < 128) {
        // ======================= LAYER 0 =======================
        const int ntile = blk;
        ushort_t* bpAh = (ushort_t*)smem;                 // 19456 B
        ushort_t* bpAl = (ushort_t*)(smem + 19456);
        ushort_t* xsh  = (ushort_t*)(smem + 38912);       // 24576 B
        ushort_t* xsl  = (ushort_t*)(smem + 63488);
        float*    zex  = (float*)(smem + 88064);          // 128*20*4 B
        unsigned* C0sub = ctr + SLOT_C0SUB + (blk & 7) * 64;

        {   // one-time LDS weight fill + zero x-frag buffers (pad cols stay 0)
            const uint_t* sh = (const uint_t*)(ws + OFF_BP0H) + (size_t)ntile * 4864;
            const uint_t* sl = (const uint_t*)(ws + OFF_BP0L) + (size_t)ntile * 4864;
            uint_t* dh = (uint_t*)bpAh; uint_t* dl = (uint_t*)bpAl;
            for (int i = tid; i < 4864; i += 512) { dh[i] = sh[i]; dl[i] = sl[i]; }
            uint_t* xz = (uint_t*)xsh;           // xsh+xsl contiguous: 12288 u32
            for (int i = tid; i < 12288; i += 512) xz[i] = 0u;
        }
        const f32x4 b0v = *(const f32x4*)&b0p[ntile * 16 + eu * 4];
        float c0v = 0.f;
        const int m = w;
        const int rowA = m * 16 + rr;
        __syncthreads();

#pragma unroll 1
        for (int t = 0; t < T_STEPS; ++t) {
            const int cur = t & 1, prv = cur ^ 1;
            ushort_t* __restrict__       h0h_cur = h0h + cur * 65536;
            ushort_t* __restrict__       h0l_cur = h0l + cur * 65536;
            const ushort_t* __restrict__ h0h_prv = h0h + prv * 65536;
            const ushort_t* __restrict__ h0l_prv = h0l + prv * 65536;

            // ---- stage x(t) as hi/lo fragments (no sync dependency) ----
#pragma unroll
            for (int i = 0; i < 18; ++i) {
                int e = tid + i * 512;                 // 128 rows x 72 feats
                int row = e / 72, k = e - row * 72;
                float v = x[(size_t)row * 72000 + (size_t)t * 72 + k];
                ushort_t hi = f2bf(v);
                ushort_t lo = f2bf(v - bf2f((short)hi));
                int di = (((row >> 4) * 3 + (k >> 5)) * 64 + ((k >> 3) & 3) * 16 + (row & 15)) * 8 + (k & 7);
                xsh[di] = hi; xsl[di] = lo;
            }
            if (tid == 0) {
                if (t >= 1) wait_ge(C0root, 128u * (unsigned)t);        // peers' h0(t-1)
                if (t >= 2) wait_ge(C1root, 128u * (unsigned)(t - 1));  // L1 done reading h0(t-2)
                __threadfence();   // acquire
            }
            __syncthreads();

            // ---- z0 = [x|h0prev] @ Bp0 : 19 s-steps, 3-pass split bf16 ----
            f32x4 aHH = {0,0,0,0}, aLH = {0,0,0,0}, aHL = {0,0,0,0};
#pragma unroll
            for (int s = 0; s < 3; ++s) {
                bf16x8 ah = *(const bf16x8*)&xsh[((m * 3 + s) * 64 + l) * 8];
                bf16x8 al = *(const bf16x8*)&xsl[((m * 3 + s) * 64 + l) * 8];
                bf16x8 bh = *(const bf16x8*)&bpAh[s * 512 + l * 8];
                bf16x8 bl = *(const bf16x8*)&bpAl[s * 512 + l * 8];
                aHH = MFMA(ah, bh, aHH); aLH = MFMA(al, bh, aLH); aHL = MFMA(ah, bl, aHL);
            }
            {
                const ushort_t* hph = h0h_prv + rowA * 512 + koff;
                const ushort_t* hpl = h0l_prv + rowA * 512 + koff;
#pragma unroll
                for (int s = 3; s < 19; ++s) {
                    bf16x8 ah = *(const bf16x8*)(hph + (s - 3) * 32);
                    bf16x8 al = *(const bf16x8*)(hpl + (s - 3) * 32);
                    bf16x8 bh = *(const bf16x8*)&bpAh[s * 512 + l * 8];
                    bf16x8 bl = *(const bf16x8*)&bpAl[s * 512 + l * 8];
                    aHH = MFMA(ah, bh, aHH); aLH = MFMA(al, bh, aLH); aHL = MFMA(ah, bl, aHL);
                }
            }
            f32x4 zv = aHH + aLH + aHL;
#pragma unroll
            for (int r = 0; r < 4; ++r)
                zex[(m * 16 + (l >> 4) * 4 + r) * 20 + rr] = zv[r];
            __syncthreads();

            // ---- epilogue: all 512 threads, (row,unit) gates, c0 in regs ----
            {
                f32x4 z = *(const f32x4*)&zex[erow * 20 + eu * 4];
                z.x += b0v.x; z.y += b0v.y; z.z += b0v.z; z.w += b0v.w;
                float ig = sigf(z.x), fg = sigf(z.y), gg = tanhfast(z.z), og = sigf(z.w);
                float cn = fg * c0v + ig * gg;
                c0v = cn;
                float hval = og * tanhfast(cn);
                ushort_t hi = f2bf(hval);
                ushort_t lo = f2bf(hval - bf2f((short)hi));
                int idx = erow * 512 + ntile * 4 + eu;
                h0h_cur[idx] = hi; h0l_cur[idx] = lo;
            }
            __syncthreads();
            if (tid == 0) { __threadfence(); publish(C0sub, C0root); }   // release h0(t)
        }
    } else {
        // ======================= LAYER 1 =======================
        const int ntile = blk - 128;
        ushort_t* bpBh = (ushort_t*)smem;                 // 32768 B
        ushort_t* bpBl = (ushort_t*)(smem + 32768);
        float* zexG = (float*)(smem + 65536);             // 10240 B
        float* zexU = (float*)(smem + 75776);             // 10240 B
        float* sqs  = (float*)(smem + 86016);             // 512 B
        float* sqq  = (float*)(smem + 86528);             // 512 B
        unsigned* C1sub = ctr + SLOT_C1SUB + (blk & 7) * 64;

        {   // one-time LDS weight fill
            const uint_t* sh = (const uint_t*)(ws + OFF_BP1H) + (size_t)ntile * 8192;
            const uint_t* sl = (const uint_t*)(ws + OFF_BP1L) + (size_t)ntile * 8192;
            uint_t* dh = (uint_t*)bpBh; uint_t* dl = (uint_t*)bpBl;
            for (int i = tid; i < 8192; i += 512) { dh[i] = sh[i]; dl[i] = sl[i]; }
        }
        const f32x4 s1v = *(const f32x4*)&s1p[ntile * 16 + eu * 4];
        const f32x4 zbv = *(const f32x4*)&zb1p[ntile * 16 + eu * 4];
        float c1v = 0.f;
        const int m = w;
        const int rowA = m * 16 + rr;
        __syncthreads();

#pragma unroll 1
        for (int t = 0; t < T_STEPS; ++t) {
            const int cur = t & 1, prv = cur ^ 1;
            const ushort_t* __restrict__ h0h_cur = h0h + cur * 65536;
            const ushort_t* __restrict__ h0l_cur = h0l + cur * 65536;
            ushort_t* __restrict__       h1h_cur = h1h + cur * 65536;
            ushort_t* __restrict__       h1l_cur = h1l + cur * 65536;
            const ushort_t* __restrict__ h1h_prv = h1h + prv * 65536;
            const ushort_t* __restrict__ h1l_prv = h1l + prv * 65536;

            if (tid == 0) {
                if (t >= 1) wait_ge(C1root, 128u * (unsigned)t);   // peers' h1(t-1)
                __threadfence();   // acquire
            }
            __syncthreads();

            // ---- U1 half: h1prev @ U1 (s = 16..31 of bpB) ----
            f32x4 uHH = {0,0,0,0}, uLH = {0,0,0,0}, uHL = {0,0,0,0};
            {
                const ushort_t* hph = h1h_prv + rowA * 512 + koff;
                const ushort_t* hpl = h1l_prv + rowA * 512 + koff;
#pragma unroll
                for (int s = 0; s < 16; ++s) {
                    bf16x8 ah = *(const bf16x8*)(hph + s * 32);
                    bf16x8 al = *(const bf16x8*)(hpl + s * 32);
                    bf16x8 bh = *(const bf16x8*)&bpBh[(16 + s) * 512 + l * 8];
                    bf16x8 bl = *(const bf16x8*)&bpBl[(16 + s) * 512 + l * 8];
                    uHH = MFMA(ah, bh, uHH); uLH = MFMA(al, bh, uLH); uHL = MFMA(ah, bl, uHL);
                }
            }
            // softmax head for step t-1 (this block's batch row), overlapped
            if (w == 7 && t > 0) ypass(h1h_prv, h1l_prv, wfT, bf, out, ntile, t - 1, l);

            if (tid == 0) {
                wait_ge(C0root, 128u * (unsigned)(t + 1));   // h0(t) published
                __threadfence();   // acquire
            }
            __syncthreads();

            // ---- G1 half: h0(t) @ G1 (s = 0..15) + fused LN stats ----
            f32x4 gHH = {0,0,0,0}, gLH = {0,0,0,0}, gHL = {0,0,0,0};
            float sa = 0.f, qa = 0.f;
            {
                const ushort_t* hph = h0h_cur + rowA * 512 + koff;
                const ushort_t* hpl = h0l_cur + rowA * 512 + koff;
#pragma unroll
                for (int s = 0; s < 16; ++s) {
                    bf16x8 ah = *(const bf16x8*)(hph + s * 32);
                    bf16x8 al = *(const bf16x8*)(hpl + s * 32);
                    bf16x8 bh = *(const bf16x8*)&bpBh[s * 512 + l * 8];
                    bf16x8 bl = *(const bf16x8*)&bpBl[s * 512 + l * 8];
                    gHH = MFMA(ah, bh, gHH); gLH = MFMA(al, bh, gLH); gHL = MFMA(ah, bl, gHL);
#pragma unroll
                    for (int j = 0; j < 8; ++j) {
                        float hv = bf2f(ah[j]) + bf2f(al[j]);
                        sa += hv; qa = fmaf(hv, hv, qa);
                    }
                }
            }
            sa += __shfl_xor(sa, 16); sa += __shfl_xor(sa, 32);
            qa += __shfl_xor(qa, 16); qa += __shfl_xor(qa, 32);
            if (l < 16) { sqs[m * 16 + l] = sa; sqq[m * 16 + l] = qa; }
            f32x4 zG = gHH + gLH + gHL, zU = uHH + uLH + uHL;
#pragma unroll
            for (int r = 0; r < 4; ++r) {
                zexG[(m * 16 + (l >> 4) * 4 + r) * 20 + rr] = zG[r];
                zexU[(m * 16 + (l >> 4) * 4 + r) * 20 + rr] = zU[r];
            }
            __syncthreads();

            // ---- epilogue: LN fold + gates, c1 in regs ----
            {
                float mu = sqs[erow] * (1.f / 512.f);
                float rs = rsqrtf(sqq[erow] * (1.f / 512.f) - mu * mu + 1e-3f);
                f32x4 zg = *(const f32x4*)&zexG[erow * 20 + eu * 4];
                f32x4 zu = *(const f32x4*)&zexU[erow * 20 + eu * 4];
                float z0 = rs * (zg.x - mu * s1v.x) + zu.x + zbv.x;
                float z1 = rs * (zg.y - mu * s1v.y) + zu.y + zbv.y;
                float z2 = rs * (zg.z - mu * s1v.z) + zu.z + zbv.z;
                float z3 = rs * (zg.w - mu * s1v.w) + zu.w + zbv.w;
                float ig = sigf(z0), fg = sigf(z1), gg = tanhfast(z2), og = sigf(z3);
                float cn = fg * c1v + ig * gg;
                c1v = cn;
                float hval = og * tanhfast(cn);
                ushort_t hi = f2bf(hval);
                ushort_t lo = f2bf(hval - bf2f((short)hi));
                int idx = erow * 512 + ntile * 4 + eu;
                h1h_cur[idx] = hi; h1l_cur[idx] = lo;
            }
            __syncthreads();
            if (tid == 0) { __threadfence(); publish(C1sub, C1root); }   // release h1(t)
        }

        // final y(T-1) after all peers publish h1(T-1)
        if (tid == 0) { wait_ge(C1root, 128u * (unsigned)T_STEPS); __threadfence(); }
        __syncthreads();
        if (w == 7)
            ypass(h1h + ((T_STEPS - 1) & 1) * 65536, h1l + ((T_STEPS - 1) & 1) * 65536,
                  wfT, bf, out, ntile, T_STEPS - 1, l);
    }
}

// ---------------- launcher ----------------
extern "C" void kernel_launch(void* const* d_in, const int* in_sizes, int n_in,
                              void* d_out, int out_size, void* d_ws, size_t ws_size,
                              hipStream_t stream)
{
    const float* x     = (const float*)d_in[0];
    const float* w0    = (const float*)d_in[1];
    const float* u0    = (const float*)d_in[2];
    const float* b0    = (const float*)d_in[3];
    const float* gamma = (const float*)d_in[4];
    const float* beta  = (const float*)d_in[5];
    const float* w1    = (const float*)d_in[6];
    const float* u1    = (const float*)d_in[7];
    const float* b1    = (const float*)d_in[8];
    const float* wf    = (const float*)d_in[9];
    const float* bf    = (const float*)d_in[10];
    float* out = (float*)d_out;
    char* ws   = (char*)d_ws;

    hipLaunchKernelGGL(pack0_kernel, dim3(128), dim3(256), 0, stream,
                       w0, u0, (ushort_t*)(ws + OFF_BP0H), (ushort_t*)(ws + OFF_BP0L));
    hipLaunchKernelGGL(pack1_kernel, dim3(128), dim3(256), 0, stream,
                       w1, u1, gamma, (ushort_t*)(ws + OFF_BP1H), (ushort_t*)(ws + OFF_BP1L));
    hipLaunchKernelGGL(sums_kernel, dim3(8), dim3(256), 0, stream,
                       w1, gamma, beta, b0, b1,
                       (float*)(ws + OFF_S1P), (float*)(ws + OFF_ZB1P), (float*)(ws + OFF_B0P));
    hipLaunchKernelGGL(wft_kernel, dim3(14), dim3(512), 0, stream, wf, (float*)(ws + OFF_WFT));
    hipLaunchKernelGGL(init_kernel, dim3(256), dim3(1024), 0, stream, ws);

    const float* xp  = x;
    const float* bfp = bf;
    char*  wsp  = ws;
    float* outp = out;
    void* args[] = { (void*)&xp, (void*)&bfp, (void*)&wsp, (void*)&outp };
    hipLaunchCooperativeKernel((void*)lstm_main, dim3(256), dim3(512), args, 0, stream);
}

// Round 7
// 33428.323 us; speedup vs baseline: 1.3325x; 1.0567x over previous
//
#include <hip/hip_runtime.h>
#include <cstdint>
#include <cstddef>

#define T_STEPS 1000
#define NU 512
#define NC 14

typedef unsigned short ushort_t;
typedef unsigned int uint_t;
typedef __attribute__((ext_vector_type(8))) short bf16x8;
typedef __attribute__((ext_vector_type(4))) float f32x4;

// ---- ws byte offsets ----
#define OFF_BP0H  0u
#define OFF_BP0L  (OFF_BP0H + 128u*9728u*2u)
#define OFF_BP1H  (OFF_BP0L + 128u*9728u*2u)
#define OFF_BP1L  (OFF_BP1H + 128u*16384u*2u)
#define OFF_S1P   (OFF_BP1L + 128u*16384u*2u)
#define OFF_ZB1P  (OFF_S1P  + 2048u*4u)
#define OFF_B0P   (OFF_ZB1P + 2048u*4u)
#define OFF_WFT   (OFF_B0P  + 2048u*4u)
#define OFF_H0H   (OFF_WFT  + 14u*512u*4u)   /* [2 buf][128 row][512 unit] ushort */
#define OFF_H0L   (OFF_H0H  + 262144u)
#define OFF_H1H   (OFF_H0L  + 262144u)
#define OFF_H1L   (OFF_H1H  + 262144u)
#define OFF_FLG0  (OFF_H1L  + 262144u)       /* 128 u32: L0 steps completed per block */
#define OFF_FLG1  (OFF_FLG0 + 512u)          /* 128 u32: L1 steps completed per block */

// ---------------- bf16 helpers ----------------
__device__ __forceinline__ float bf2f(short s) {
    unsigned u = ((unsigned)(unsigned short)s) << 16;
    return __builtin_bit_cast(float, u);
}
__device__ __forceinline__ ushort_t f2bf(float f) {
    unsigned u = __float_as_uint(f);
    u = u + 0x7FFFu + ((u >> 16) & 1u);   // RNE
    return (ushort_t)(u >> 16);
}

// ---------------- weight packing (layouts unchanged) ----------------
__global__ void pack0_kernel(const float* __restrict__ w0, const float* __restrict__ u0,
                             ushort_t* __restrict__ bp0h, ushort_t* __restrict__ bp0l)
{
    const int ntile = blockIdx.x;
    const int l = threadIdx.x & 63;
    const int c = l & 15, koff = (l >> 4) * 8;
    const int zcol = ntile * 4 + (c >> 2) + 512 * (c & 3);
    for (int s = (threadIdx.x >> 6); s < 19; s += 4) {
        bf16x8 hv, lv;
#pragma unroll
        for (int j = 0; j < 8; ++j) {
            int k = s * 32 + koff + j;
            float v;
            if (k < 96) v = (k < 72) ? w0[(size_t)k * 2048 + zcol] : 0.f;
            else        v = u0[(size_t)(k - 96) * 2048 + zcol];
            ushort_t hi = f2bf(v);
            ushort_t lo = f2bf(v - bf2f((short)hi));
            hv[j] = (short)hi; lv[j] = (short)lo;
        }
        size_t di = ((size_t)(ntile * 19 + s) * 64 + l) * 8;
        *(bf16x8*)&bp0h[di] = hv;
        *(bf16x8*)&bp0l[di] = lv;
    }
}

__global__ void pack1_kernel(const float* __restrict__ w1, const float* __restrict__ u1,
                             const float* __restrict__ gamma,
                             ushort_t* __restrict__ bp1h, ushort_t* __restrict__ bp1l)
{
    const int ntile = blockIdx.x;
    const int l = threadIdx.x & 63;
    const int c = l & 15, koff = (l >> 4) * 8;
    const int zcol = ntile * 4 + (c >> 2) + 512 * (c & 3);
    for (int s = (threadIdx.x >> 6); s < 32; s += 4) {
        bf16x8 hv, lv;
#pragma unroll
        for (int j = 0; j < 8; ++j) {
            int k = s * 32 + koff + j;
            float v = (k < 512) ? gamma[k] * w1[(size_t)k * 2048 + zcol]
                                : u1[(size_t)(k - 512) * 2048 + zcol];
            ushort_t hi = f2bf(v);
            ushort_t lo = f2bf(v - bf2f((short)hi));
            hv[j] = (short)hi; lv[j] = (short)lo;
        }
        size_t di = ((size_t)(ntile * 32 + s) * 64 + l) * 8;
        *(bf16x8*)&bp1h[di] = hv;
        *(bf16x8*)&bp1l[di] = lv;
    }
}

__global__ void sums_kernel(const float* __restrict__ w1, const float* __restrict__ gamma,
                            const float* __restrict__ beta, const float* __restrict__ b0,
                            const float* __restrict__ b1,
                            float* __restrict__ s1p, float* __restrict__ zb1p,
                            float* __restrict__ b0p)
{
    int zcol = blockIdx.x * 256 + threadIdx.x;   // 8 blocks * 256
    float gs = 0.f, bs = 0.f;
    for (int k = 0; k < NU; k++) {
        float w = w1[(size_t)k * 2048 + zcol];
        gs += gamma[k] * w;
        bs += beta[k] * w;
    }
    int g = zcol >> 9, r = zcol & 511, nt = r >> 2, u = r & 3;
    int pc = nt * 16 + u * 4 + g;
    s1p[pc]  = gs;
    zb1p[pc] = b1[zcol] + bs;
    b0p[pc]  = b0[zcol];
}

__global__ void wft_kernel(const float* __restrict__ wf, float* __restrict__ wfT)
{
    int i = blockIdx.x * 512 + threadIdx.x;   // 14 blocks * 512
    if (i < NC * NU) {
        int c = i >> 9, u = i & 511;
        wfT[c * NU + u] = wf[(size_t)u * NC + c];
    }
}

__global__ void init_kernel(char* __restrict__ ws)
{
    size_t i = (size_t)blockIdx.x * 1024 + threadIdx.x;   // 256*1024
    uint_t* st = (uint_t*)(ws + OFF_H0H);                  // 1 MB h-state
    if (i < 262144) st[i] = 0u;
    if (i < 256) ((uint_t*)(ws + OFF_FLG0))[i] = 0u;       // FLG0+FLG1 contiguous
}

// ---------------- device helpers ----------------
__device__ __forceinline__ float sigf(float x)     { return 1.f / (1.f + __expf(-x)); }
__device__ __forceinline__ float tanhfast(float x) { return 2.f / (1.f + __expf(-2.f * x)) - 1.f; }

// wave-0 poll: all 128 producer flags >= tgt (64 lanes x 2 loads, no RMW)
__device__ __forceinline__ void wave_wait(const unsigned* f, unsigned tgt, int l)
{
    while (true) {
        unsigned a = __hip_atomic_load(f + l,      __ATOMIC_RELAXED, __HIP_MEMORY_SCOPE_AGENT);
        unsigned b = __hip_atomic_load(f + 64 + l, __ATOMIC_RELAXED, __HIP_MEMORY_SCOPE_AGENT);
        if (__all((a >= tgt) && (b >= tgt))) return;
        __builtin_amdgcn_s_sleep(2);
    }
}
__device__ __forceinline__ void wave_wait2(const unsigned* f0, unsigned t0,
                                           const unsigned* f1, unsigned t1, int l)
{
    while (true) {
        unsigned a0 = __hip_atomic_load(f0 + l,      __ATOMIC_RELAXED, __HIP_MEMORY_SCOPE_AGENT);
        unsigned b0 = __hip_atomic_load(f0 + 64 + l, __ATOMIC_RELAXED, __HIP_MEMORY_SCOPE_AGENT);
        unsigned a1 = __hip_atomic_load(f1 + l,      __ATOMIC_RELAXED, __HIP_MEMORY_SCOPE_AGENT);
        unsigned b1 = __hip_atomic_load(f1 + 64 + l, __ATOMIC_RELAXED, __HIP_MEMORY_SCOPE_AGENT);
        if (__all((a0 >= t0) && (b0 >= t0) && (a1 >= t1) && (b1 >= t1))) return;
        __builtin_amdgcn_s_sleep(2);
    }
}
// single release store, no serialization (caller: tid==0 after __syncthreads)
__device__ __forceinline__ void publish_flag(unsigned* f, int idx, unsigned val)
{
    __threadfence();   // release: drain dirty L2 to coherence point
    __hip_atomic_store(f + idx, val, __ATOMIC_RELAXED, __HIP_MEMORY_SCOPE_AGENT);
}

// softmax head for one batch row; h1 stored as bf16 hi/lo [128][512]
__device__ void ypass(const ushort_t* __restrict__ h1h, const ushort_t* __restrict__ h1l,
                      const float* __restrict__ wfT, const float* __restrict__ bf,
                      float* __restrict__ out, int b, int tw, int lane)
{
    bf16x8 hh = *(const bf16x8*)(h1h + (size_t)b * NU + lane * 8);
    bf16x8 hl = *(const bf16x8*)(h1l + (size_t)b * NU + lane * 8);
    float hv[8];
#pragma unroll
    for (int j = 0; j < 8; ++j) hv[j] = bf2f(hh[j]) + bf2f(hl[j]);
    float z[NC];
#pragma unroll
    for (int c = 0; c < NC; ++c) {
        const float* wp = wfT + c * NU + lane * 8;
        float a = 0.f;
#pragma unroll
        for (int j = 0; j < 8; ++j) a = fmaf(hv[j], wp[j], a);
        z[c] = a;
    }
#pragma unroll
    for (int off = 32; off > 0; off >>= 1) {
#pragma unroll
        for (int c = 0; c < NC; ++c) z[c] += __shfl_xor(z[c], off);
    }
    if (lane == 0) {
        float mx = -1e30f;
#pragma unroll
        for (int c = 0; c < NC; ++c) { z[c] += bf[c]; mx = fmaxf(mx, z[c]); }
        float s = 0.f, e[NC];
#pragma unroll
        for (int c = 0; c < NC; ++c) { e[c] = __expf(z[c] - mx); s += e[c]; }
        float inv = 1.f / s;
        float* o = out + ((size_t)b * T_STEPS + tw) * NC;
#pragma unroll
        for (int c = 0; c < NC; ++c) o[c] = e[c] * inv;
    }
}

// ---------------- main persistent kernel ----------------
// blocks 0..127   : layer-0 pipeline, ntile = blk,     M=128, K=608
// blocks 128..255 : layer-1 pipeline, ntile = blk-128, M=128, K=1024 (G1|U1)
#define MFMA(A,B,C) __builtin_amdgcn_mfma_f32_16x16x32_bf16((A),(B),(C),0,0,0)

__global__ __launch_bounds__(512, 1)
void lstm_main(const float* __restrict__ x, const float* __restrict__ bf,
               char* __restrict__ ws, float* __restrict__ out)
{
    __shared__ __attribute__((aligned(16))) unsigned char smem[115712];

    const float* __restrict__ s1p  = (const float*)(ws + OFF_S1P);
    const float* __restrict__ zb1p = (const float*)(ws + OFF_ZB1P);
    const float* __restrict__ b0p  = (const float*)(ws + OFF_B0P);
    const float* __restrict__ wfTg = (const float*)(ws + OFF_WFT);
    ushort_t* h0h = (ushort_t*)(ws + OFF_H0H);
    ushort_t* h0l = (ushort_t*)(ws + OFF_H0L);
    ushort_t* h1h = (ushort_t*)(ws + OFF_H1H);
    ushort_t* h1l = (ushort_t*)(ws + OFF_H1L);
    unsigned* flag0 = (unsigned*)(ws + OFF_FLG0);
    unsigned* flag1 = (unsigned*)(ws + OFF_FLG1);

    const int tid  = threadIdx.x;
    const int l    = tid & 63;
    const int w    = tid >> 6;
    const int rr   = l & 15;
    const int koff = (l >> 4) * 8;
    const int blk  = blockIdx.x;
    const int erow = tid >> 2, eu = tid & 3;   // epilogue mapping: row, unit

    if (blk < 128) {
        // ======================= LAYER 0 =======================
        const int ntile = blk;
        ushort_t* bpAh = (ushort_t*)smem;                 // 19456 B
        ushort_t* bpAl = (ushort_t*)(smem + 19456);
        ushort_t* xsh  = (ushort_t*)(smem + 38912);       // 24576 B
        ushort_t* xsl  = (ushort_t*)(smem + 63488);
        float*    zex  = (float*)(smem + 88064);          // 128*20*4 B

        {   // one-time LDS weight fill + zero x-frag buffers (pad cols stay 0)
            const uint_t* sh = (const uint_t*)(ws + OFF_BP0H) + (size_t)ntile * 4864;
            const uint_t* sl = (const uint_t*)(ws + OFF_BP0L) + (size_t)ntile * 4864;
            uint_t* dh = (uint_t*)bpAh; uint_t* dl = (uint_t*)bpAl;
            for (int i = tid; i < 4864; i += 512) { dh[i] = sh[i]; dl[i] = sl[i]; }
            uint_t* xz = (uint_t*)xsh;           // xsh+xsl contiguous: 12288 u32
            for (int i = tid; i < 12288; i += 512) xz[i] = 0u;
        }
        const f32x4 b0v = *(const f32x4*)&b0p[ntile * 16 + eu * 4];
        float c0v = 0.f;
        const int m = w;
        const int rowA = m * 16 + rr;

        // prefetch x(0) into registers
        float xr[18];
#pragma unroll
        for (int i = 0; i < 18; ++i) {
            int e = tid + i * 512, row = e / 72, k = e - row * 72;
            xr[i] = x[(size_t)row * 72000 + k];
        }
        __syncthreads();

#pragma unroll 1
        for (int t = 0; t < T_STEPS; ++t) {
            const int cur = t & 1, prv = cur ^ 1;
            ushort_t* __restrict__       h0h_cur = h0h + cur * 65536;
            ushort_t* __restrict__       h0l_cur = h0l + cur * 65536;
            const ushort_t* __restrict__ h0h_prv = h0h + prv * 65536;
            const ushort_t* __restrict__ h0l_prv = h0l + prv * 65536;

            // ---- store prefetched x(t) as hi/lo fragments ----
#pragma unroll
            for (int i = 0; i < 18; ++i) {
                int e = tid + i * 512, row = e / 72, k = e - row * 72;
                float v = xr[i];
                ushort_t hi = f2bf(v);
                ushort_t lo = f2bf(v - bf2f((short)hi));
                int di = (((row >> 4) * 3 + (k >> 5)) * 64 + ((k >> 3) & 3) * 16 + (row & 15)) * 8 + (k & 7);
                xsh[di] = hi; xsl[di] = lo;
            }
            __syncthreads();   // xs(t) ready

            // ---- x-part MFMA (s=0..2) — recurrence-free, before the wait ----
            f32x4 aHH = {0,0,0,0}, aLH = {0,0,0,0}, aHL = {0,0,0,0};
#pragma unroll
            for (int s = 0; s < 3; ++s) {
                bf16x8 ah = *(const bf16x8*)&xsh[((m * 3 + s) * 64 + l) * 8];
                bf16x8 al = *(const bf16x8*)&xsl[((m * 3 + s) * 64 + l) * 8];
                bf16x8 bh = *(const bf16x8*)&bpAh[s * 512 + l * 8];
                bf16x8 bl = *(const bf16x8*)&bpAl[s * 512 + l * 8];
                aHH = MFMA(ah, bh, aHH); aLH = MFMA(al, bh, aLH); aHL = MFMA(ah, bl, aHL);
            }
            // prefetch x(t+1)
            if (t + 1 < T_STEPS) {
#pragma unroll
                for (int i = 0; i < 18; ++i) {
                    int e = tid + i * 512, row = e / 72, k = e - row * 72;
                    xr[i] = x[(size_t)row * 72000 + (size_t)(t + 1) * 72 + k];
                }
            }
            // ---- wait: peers' h0(t-1); L1 done reading h0(t-2) ----
            if (w == 0 && t >= 1) {
                wave_wait2(flag0, (unsigned)t, flag1, (t >= 2) ? (unsigned)(t - 1) : 0u, l);
                __threadfence();   // acquire
            }
            __syncthreads();

            // ---- h-part MFMA (s=3..18) ----
            {
                const ushort_t* hph = h0h_prv + rowA * 512 + koff;
                const ushort_t* hpl = h0l_prv + rowA * 512 + koff;
#pragma unroll
                for (int s = 3; s < 19; ++s) {
                    bf16x8 ah = *(const bf16x8*)(hph + (s - 3) * 32);
                    bf16x8 al = *(const bf16x8*)(hpl + (s - 3) * 32);
                    bf16x8 bh = *(const bf16x8*)&bpAh[s * 512 + l * 8];
                    bf16x8 bl = *(const bf16x8*)&bpAl[s * 512 + l * 8];
                    aHH = MFMA(ah, bh, aHH); aLH = MFMA(al, bh, aLH); aHL = MFMA(ah, bl, aHL);
                }
            }
            f32x4 zv = aHH + aLH + aHL;
#pragma unroll
            for (int r = 0; r < 4; ++r)
                zex[(m * 16 + (l >> 4) * 4 + r) * 20 + rr] = zv[r];
            __syncthreads();

            // ---- epilogue: gates, c0 in regs ----
            {
                f32x4 z = *(const f32x4*)&zex[erow * 20 + eu * 4];
                z.x += b0v.x; z.y += b0v.y; z.z += b0v.z; z.w += b0v.w;
                float ig = sigf(z.x), fg = sigf(z.y), gg = tanhfast(z.z), og = sigf(z.w);
                float cn = fg * c0v + ig * gg;
                c0v = cn;
                float hval = og * tanhfast(cn);
                ushort_t hi = f2bf(hval);
                ushort_t lo = f2bf(hval - bf2f((short)hi));
                int idx = erow * 512 + ntile * 4 + eu;
                h0h_cur[idx] = hi; h0l_cur[idx] = lo;
            }
            __syncthreads();
            if (tid == 0) publish_flag(flag0, blk, (unsigned)(t + 1));
        }
    } else {
        // ======================= LAYER 1 =======================
        const int ntile = blk - 128;
        ushort_t* bpBh = (ushort_t*)smem;                 // 32768 B
        ushort_t* bpBl = (ushort_t*)(smem + 32768);
        float* wfTl = (float*)(smem + 65536);             // 28672 B
        float* zexG = (float*)(smem + 94208);             // 10240 B
        float* zexU = (float*)(smem + 104448);            // 10240 B
        float* sqs  = (float*)(smem + 114688);            // 512 B
        float* sqq  = (float*)(smem + 115200);            // 512 B

        {   // one-time LDS fill: weights + wfT
            const uint_t* sh = (const uint_t*)(ws + OFF_BP1H) + (size_t)ntile * 8192;
            const uint_t* sl = (const uint_t*)(ws + OFF_BP1L) + (size_t)ntile * 8192;
            uint_t* dh = (uint_t*)bpBh; uint_t* dl = (uint_t*)bpBl;
            for (int i = tid; i < 8192; i += 512) { dh[i] = sh[i]; dl[i] = sl[i]; }
            for (int i = tid; i < 7168; i += 512) wfTl[i] = wfTg[i];
        }
        const f32x4 s1v = *(const f32x4*)&s1p[ntile * 16 + eu * 4];
        const f32x4 zbv = *(const f32x4*)&zb1p[ntile * 16 + eu * 4];
        float c1v = 0.f;
        const int m = w;
        const int rowA = m * 16 + rr;
        __syncthreads();

#pragma unroll 1
        for (int t = 0; t < T_STEPS; ++t) {
            const int cur = t & 1, prv = cur ^ 1;
            const ushort_t* __restrict__ h0h_cur = h0h + cur * 65536;
            const ushort_t* __restrict__ h0l_cur = h0l + cur * 65536;
            ushort_t* __restrict__       h1h_cur = h1h + cur * 65536;
            ushort_t* __restrict__       h1l_cur = h1l + cur * 65536;
            const ushort_t* __restrict__ h1h_prv = h1h + prv * 65536;
            const ushort_t* __restrict__ h1l_prv = h1l + prv * 65536;

            if (w == 0 && t >= 1) {
                wave_wait(flag1, (unsigned)t, l);   // peers' h1(t-1)
                __threadfence();   // acquire
            }
            __syncthreads();

            // ---- U1 half: h1prev @ U1 (s = 16..31 of bpB) ----
            f32x4 uHH = {0,0,0,0}, uLH = {0,0,0,0}, uHL = {0,0,0,0};
            {
                const ushort_t* hph = h1h_prv + rowA * 512 + koff;
                const ushort_t* hpl = h1l_prv + rowA * 512 + koff;
#pragma unroll
                for (int s = 0; s < 16; ++s) {
                    bf16x8 ah = *(const bf16x8*)(hph + s * 32);
                    bf16x8 al = *(const bf16x8*)(hpl + s * 32);
                    bf16x8 bh = *(const bf16x8*)&bpBh[(16 + s) * 512 + l * 8];
                    bf16x8 bl = *(const bf16x8*)&bpBl[(16 + s) * 512 + l * 8];
                    uHH = MFMA(ah, bh, uHH); uLH = MFMA(al, bh, uLH); uHL = MFMA(ah, bl, uHL);
                }
            }
            // softmax head for step t-1 (this block's batch row), overlapped with wait
            if (w == 7 && t > 0) ypass(h1h_prv, h1l_prv, wfTl, bf, out, ntile, t - 1, l);

            if (w == 0) {
                wave_wait(flag0, (unsigned)(t + 1), l);   // h0(t) published by all L0
                __threadfence();   // acquire
            }
            __syncthreads();

            // ---- G1 half: h0(t) @ G1 (s = 0..15) + fused LN stats ----
            f32x4 gHH = {0,0,0,0}, gLH = {0,0,0,0}, gHL = {0,0,0,0};
            float sa = 0.f, qa = 0.f;
            {
                const ushort_t* hph = h0h_cur + rowA * 512 + koff;
                const ushort_t* hpl = h0l_cur + rowA * 512 + koff;
#pragma unroll
                for (int s = 0; s < 16; ++s) {
                    bf16x8 ah = *(const bf16x8*)(hph + s * 32);
                    bf16x8 al = *(const bf16x8*)(hpl + s * 32);
                    bf16x8 bh = *(const bf16x8*)&bpBh[s * 512 + l * 8];
                    bf16x8 bl = *(const bf16x8*)&bpBl[s * 512 + l * 8];
                    gHH = MFMA(ah, bh, gHH); gLH = MFMA(al, bh, gLH); gHL = MFMA(ah, bl, gHL);
#pragma unroll
                    for (int j = 0; j < 8; ++j) {
                        float hv = bf2f(ah[j]) + bf2f(al[j]);
                        sa += hv; qa = fmaf(hv, hv, qa);
                    }
                }
            }
            sa += __shfl_xor(sa, 16); sa += __shfl_xor(sa, 32);
            qa += __shfl_xor(qa, 16); qa += __shfl_xor(qa, 32);
            if (l < 16) { sqs[m * 16 + l] = sa; sqq[m * 16 + l] = qa; }
            f32x4 zG = gHH + gLH + gHL, zU = uHH + uLH + uHL;
#pragma unroll
            for (int r = 0; r < 4; ++r) {
                zexG[(m * 16 + (l >> 4) * 4 + r) * 20 + rr] = zG[r];
                zexU[(m * 16 + (l >> 4) * 4 + r) * 20 + rr] = zU[r];
            }
            __syncthreads();

            // ---- epilogue: LN fold + gates, c1 in regs ----
            {
                float mu = sqs[erow] * (1.f / 512.f);
                float rs = rsqrtf(sqq[erow] * (1.f / 512.f) - mu * mu + 1e-3f);
                f32x4 zg = *(const f32x4*)&zexG[erow * 20 + eu * 4];
                f32x4 zu = *(const f32x4*)&zexU[erow * 20 + eu * 4];
                float z0 = rs * (zg.x - mu * s1v.x) + zu.x + zbv.x;
                float z1 = rs * (zg.y - mu * s1v.y) + zu.y + zbv.y;
                float z2 = rs * (zg.z - mu * s1v.z) + zu.z + zbv.z;
                float z3 = rs * (zg.w - mu * s1v.w) + zu.w + zbv.w;
                float ig = sigf(z0), fg = sigf(z1), gg = tanhfast(z2), og = sigf(z3);
                float cn = fg * c1v + ig * gg;
                c1v = cn;
                float hval = og * tanhfast(cn);
                ushort_t hi = f2bf(hval);
                ushort_t lo = f2bf(hval - bf2f((short)hi));
                int idx = erow * 512 + ntile * 4 + eu;
                h1h_cur[idx] = hi; h1l_cur[idx] = lo;
            }
            __syncthreads();
            if (tid == 0) publish_flag(flag1, ntile, (unsigned)(t + 1));
        }

        // final y(T-1) after all peers publish h1(T-1)
        if (w == 0) { wave_wait(flag1, (unsigned)T_STEPS, l); __threadfence(); }
        __syncthreads();
        if (w == 7)
            ypass(h1h + ((T_STEPS - 1) & 1) * 65536, h1l + ((T_STEPS - 1) & 1) * 65536,
                  wfTl, bf, out, ntile, T_STEPS - 1, l);
    }
}

// ---------------- launcher ----------------
extern "C" void kernel_launch(void* const* d_in, const int* in_sizes, int n_in,
                              void* d_out, int out_size, void* d_ws, size_t ws_size,
                              hipStream_t stream)
{
    const float* x     = (const float*)d_in[0];
    const float* w0    = (const float*)d_in[1];
    const float* u0    = (const float*)d_in[2];
    const float* b0    = (const float*)d_in[3];
    const float* gamma = (const float*)d_in[4];
    const float* beta  = (const float*)d_in[5];
    const float* w1    = (const float*)d_in[6];
    const float* u1    = (const float*)d_in[7];
    const float* b1    = (const float*)d_in[8];
    const float* wf    = (const float*)d_in[9];
    const float* bf    = (const float*)d_in[10];
    float* out = (float*)d_out;
    char* ws   = (char*)d_ws;

    hipLaunchKernelGGL(pack0_kernel, dim3(128), dim3(256), 0, stream,
                       w0, u0, (ushort_t*)(ws + OFF_BP0H), (ushort_t*)(ws + OFF_BP0L));
    hipLaunchKernelGGL(pack1_kernel, dim3(128), dim3(256), 0, stream,
                       w1, u1, gamma, (ushort_t*)(ws + OFF_BP1H), (ushort_t*)(ws + OFF_BP1L));
    hipLaunchKernelGGL(sums_kernel, dim3(8), dim3(256), 0, stream,
                       w1, gamma, beta, b0, b1,
                       (float*)(ws + OFF_S1P), (float*)(ws + OFF_ZB1P), (float*)(ws + OFF_B0P));
    hipLaunchKernelGGL(wft_kernel, dim3(14), dim3(512), 0, stream, wf, (float*)(ws + OFF_WFT));
    hipLaunchKernelGGL(init_kernel, dim3(256), dim3(1024), 0, stream, ws);

    const float* xp  = x;
    const float* bfp = bf;
    char*  wsp  = ws;
    float* outp = out;
    void* args[] = { (void*)&xp, (void*)&bfp, (void*)&wsp, (void*)&outp };
    hipLaunchCooperativeKernel((void*)lstm_main, dim3(256), dim3(512), args, 0, stream);
}